// Round 3
// baseline (266.353 us; speedup 1.0000x reference)
//
#include <hip/hip_runtime.h>
#include <stdint.h>

// Problem constants (match reference)
#define NV1 200000
#define NLM 50000
#define NTOT 250000        // NV1 + NLM
#define TLEN 600
#define UU 10
#define NNZV1 800000
#define NNZLM 200000
#define NELEM (TLEN * UU)  // 6000 poisson elements

// ---------------- threefry2x32 (bit-exact JAX implementation) ----------------
__device__ __forceinline__ void tf2x32(uint32_t k0, uint32_t k1,
                                       uint32_t c0, uint32_t c1,
                                       uint32_t& o0, uint32_t& o1) {
  const uint32_t ks2 = k0 ^ k1 ^ 0x1BD11BDAu;
  uint32_t x0 = c0 + k0;
  uint32_t x1 = c1 + k1;
#define TF_RND(r) { x0 += x1; x1 = (x1 << (r)) | (x1 >> (32 - (r))); x1 ^= x0; }
  TF_RND(13) TF_RND(15) TF_RND(26) TF_RND(6)
  x0 += k1;  x1 += ks2 + 1u;
  TF_RND(17) TF_RND(29) TF_RND(16) TF_RND(24)
  x0 += ks2; x1 += k0 + 2u;
  TF_RND(13) TF_RND(15) TF_RND(26) TF_RND(6)
  x0 += k0;  x1 += k1 + 3u;
  TF_RND(17) TF_RND(29) TF_RND(16) TF_RND(24)
  x0 += k1;  x1 += ks2 + 4u;
  TF_RND(13) TF_RND(15) TF_RND(26) TF_RND(6)
  x0 += ks2; x1 += k0 + 5u;
#undef TF_RND
  o0 = x0; o1 = x1;
}

// ---------------- Poisson spikes, JAX partitionable-threefry semantics ------
// (verified bit-exact vs harness in round 2: absmax 0.0625 from scatter order)
__global__ void spikes_kernel(float* __restrict__ spikes) {
  const int e = blockIdx.x * blockDim.x + threadIdx.x;
  if (e >= NELEM) return;

  uint32_t r0 = 0u, r1 = 42u;   // threefry_seed(42) = (0, 42)
  float S = 0.0f;
  int result = 63;
  for (int iter = 0; iter < 64; ++iter) {
    uint32_t n0, n1, s0, s1;
    tf2x32(r0, r1, 0u, 0u, n0, n1);   // new rng = hash(rng, (0,0)) full pair
    tf2x32(r0, r1, 0u, 1u, s0, s1);   // subkey  = hash(rng, (0,1)) full pair
    r0 = n0; r1 = n1;

    uint32_t h0, h1;
    tf2x32(s0, s1, 0u, (uint32_t)e, h0, h1);
    const uint32_t bits = h0 ^ h1;    // 32-bit fold of 64-bit hash output
    const float u = __uint_as_float((bits >> 9) | 0x3f800000u) - 1.0f;
    S += logf(u);                     // f32 accumulate, matches jnp.log chain
    if (!(S > -1.0f)) { result = iter; break; }
  }
  spikes[e] = (float)result;
}

// ---------------- zero W with a full-width grid (replaces slow rocclr fill) -
// NTOT*UU = 2,500,000 floats = 625,000 float4 exactly.
#define WZ4 (NTOT * UU / 4)
__global__ void __launch_bounds__(256) zeroW_kernel(float4* __restrict__ W4) {
  const int i = blockIdx.x * 256 + threadIdx.x;
  if (i < WZ4) W4[i] = make_float4(0.f, 0.f, 0.f, 0.f);
}

// ---------------- COO scatter-add into dense W (n x 10) ---------------------
__global__ void scatter_kernel(const float* __restrict__ w,
                               const int* __restrict__ rows,
                               const int* __restrict__ cols,
                               int nnz, float* __restrict__ W) {
  const int i = blockIdx.x * blockDim.x + threadIdx.x;
  if (i >= nnz) return;
  atomicAdd(&W[(size_t)rows[i] * UU + cols[i]], w[i]);
}

// ---------------- Main: out[t,n] = sum_u spikes[t,u] * W[n,u] ---------------
// Each thread owns 4 consecutive n (float4 stores), loops over a 150-row
// t-tile with the spike slab in LDS (uniform broadcast reads).
#define TTILE 150
#define NT4 (NTOT / 4)        // 62500 threads per t-tile
__global__ void __launch_bounds__(256) out_kernel(const float* __restrict__ W,
                                                  const float* __restrict__ spikes,
                                                  float* __restrict__ out) {
  __shared__ float s[TTILE * UU];
  const int t0 = blockIdx.y * TTILE;
  for (int i = threadIdx.x; i < TTILE * UU; i += 256)
    s[i] = spikes[t0 * UU + i];
  __syncthreads();

  const int n4 = blockIdx.x * 256 + threadIdx.x;
  if (n4 >= NT4) return;
  const int n = n4 * 4;

  float w[4][UU];
#pragma unroll
  for (int r = 0; r < 4; ++r)
#pragma unroll
    for (int u = 0; u < UU; ++u)
      w[r][u] = W[(size_t)(n + r) * UU + u];

  for (int t = 0; t < TTILE; ++t) {
    float4 acc;
    float* ap = &acc.x;
#pragma unroll
    for (int r = 0; r < 4; ++r) {
      float a = 0.0f;
#pragma unroll
      for (int u = 0; u < UU; ++u)
        a = fmaf(s[t * UU + u], w[r][u], a);
      ap[r] = a;
    }
    *reinterpret_cast<float4*>(&out[(size_t)(t0 + t) * NTOT + n]) = acc;
  }
}

extern "C" void kernel_launch(void* const* d_in, const int* in_sizes, int n_in,
                              void* d_out, int out_size, void* d_ws, size_t ws_size,
                              hipStream_t stream) {
  // Input order: inp, w_v1, rows_v1, cols_v1, w_lm, rows_lm, cols_lm
  const float* w_v1   = (const float*)d_in[1];
  const int*   rows_v1 = (const int*)d_in[2];
  const int*   cols_v1 = (const int*)d_in[3];
  const float* w_lm   = (const float*)d_in[4];
  const int*   rows_lm = (const int*)d_in[5];
  const int*   cols_lm = (const int*)d_in[6];
  float* out = (float*)d_out;

  // Workspace layout: W (250000 x 10 f32 = 10 MB), then spikes (6000 f32)
  float* W = (float*)d_ws;
  float* spikes = W + (size_t)NTOT * UU;
  const size_t need = ((size_t)NTOT * UU + NELEM) * sizeof(float);
  if (ws_size < need) return;  // fail loudly via validation

  // 1) zero dense W (custom kernel; rocclr fillBuffer ran at 27 GB/s)
  zeroW_kernel<<<(WZ4 + 255) / 256, 256, 0, stream>>>((float4*)W);

  // 2) deterministic Poisson spikes (JAX partitionable threefry replica)
  spikes_kernel<<<(NELEM + 255) / 256, 256, 0, stream>>>(spikes);

  // 3) scatter COO weights: v1 rows at [0,200000), lm rows appended after
  scatter_kernel<<<(NNZV1 + 255) / 256, 256, 0, stream>>>(w_v1, rows_v1, cols_v1,
                                                          NNZV1, W);
  scatter_kernel<<<(NNZLM + 255) / 256, 256, 0, stream>>>(w_lm, rows_lm, cols_lm,
                                                          NNZLM, W + (size_t)NV1 * UU);

  // 4) big streaming output: (600 x 250000) f32
  dim3 grid((NT4 + 255) / 256, TLEN / TTILE);
  out_kernel<<<grid, 256, 0, stream>>>(W, spikes, out);
}

// Round 5
// 189.890 us; speedup vs baseline: 1.4027x; 1.4027x over previous
//
#include <hip/hip_runtime.h>
#include <stdint.h>

// Problem constants (match reference)
#define NV1 200000
#define NLM 50000
#define NTOT 250000        // NV1 + NLM
#define TLEN 600
#define UU 10
#define NNZV1 800000
#define NNZLM 200000
#define NELEM (TLEN * UU)  // 6000 poisson elements

typedef float f32x4 __attribute__((ext_vector_type(4)));

// ---------------- threefry2x32 (bit-exact JAX implementation) ----------------
__device__ __forceinline__ void tf2x32(uint32_t k0, uint32_t k1,
                                       uint32_t c0, uint32_t c1,
                                       uint32_t& o0, uint32_t& o1) {
  const uint32_t ks2 = k0 ^ k1 ^ 0x1BD11BDAu;
  uint32_t x0 = c0 + k0;
  uint32_t x1 = c1 + k1;
#define TF_RND(r) { x0 += x1; x1 = (x1 << (r)) | (x1 >> (32 - (r))); x1 ^= x0; }
  TF_RND(13) TF_RND(15) TF_RND(26) TF_RND(6)
  x0 += k1;  x1 += ks2 + 1u;
  TF_RND(17) TF_RND(29) TF_RND(16) TF_RND(24)
  x0 += ks2; x1 += k0 + 2u;
  TF_RND(13) TF_RND(15) TF_RND(26) TF_RND(6)
  x0 += k0;  x1 += k1 + 3u;
  TF_RND(17) TF_RND(29) TF_RND(16) TF_RND(24)
  x0 += k1;  x1 += ks2 + 4u;
  TF_RND(13) TF_RND(15) TF_RND(26) TF_RND(6)
  x0 += ks2; x1 += k0 + 5u;
#undef TF_RND
  o0 = x0; o1 = x1;
}

// ---------------- Poisson spikes, JAX partitionable-threefry semantics ------
// (verified bit-exact vs harness in round 2)
__global__ void spikes_kernel(float* __restrict__ spikes) {
  const int e = blockIdx.x * blockDim.x + threadIdx.x;
  if (e >= NELEM) return;

  uint32_t r0 = 0u, r1 = 42u;   // threefry_seed(42) = (0, 42)
  float S = 0.0f;
  int result = 63;
  for (int iter = 0; iter < 64; ++iter) {
    uint32_t n0, n1, s0, s1;
    tf2x32(r0, r1, 0u, 0u, n0, n1);   // new rng = hash(rng, (0,0)) full pair
    tf2x32(r0, r1, 0u, 1u, s0, s1);   // subkey  = hash(rng, (0,1)) full pair
    r0 = n0; r1 = n1;

    uint32_t h0, h1;
    tf2x32(s0, s1, 0u, (uint32_t)e, h0, h1);
    const uint32_t bits = h0 ^ h1;    // 32-bit fold of 64-bit hash output
    const float u = __uint_as_float((bits >> 9) | 0x3f800000u) - 1.0f;
    S += logf(u);
    if (!(S > -1.0f)) { result = iter; break; }
  }
  spikes[e] = (float)result;
}

// ---------------- zero WT with a full-width grid ----------------------------
#define WZ4 (NTOT * UU / 4)   // 625,000 float4
__global__ void __launch_bounds__(256) zeroW_kernel(f32x4* __restrict__ W4) {
  const int i = blockIdx.x * 256 + threadIdx.x;
  if (i < WZ4) W4[i] = (f32x4)(0.f);
}

// ---------------- fused COO scatter-add into transposed WT (u x NTOT) -------
#define NNZTOT (NNZV1 + NNZLM)
__global__ void scatter_kernel(const float* __restrict__ w_v1,
                               const int* __restrict__ rows_v1,
                               const int* __restrict__ cols_v1,
                               const float* __restrict__ w_lm,
                               const int* __restrict__ rows_lm,
                               const int* __restrict__ cols_lm,
                               float* __restrict__ WT) {
  const int i = blockIdx.x * blockDim.x + threadIdx.x;
  if (i >= NNZTOT) return;
  if (i < NNZV1) {
    atomicAdd(&WT[(size_t)cols_v1[i] * NTOT + rows_v1[i]], w_v1[i]);
  } else {
    const int j = i - NNZV1;
    atomicAdd(&WT[(size_t)cols_lm[j] * NTOT + NV1 + rows_lm[j]], w_lm[j]);
  }
}

// ---------------- Main: out[t,n] = sum_u spikes[t,u] * WT[u,n] --------------
// Thread owns 4 consecutive n. WT loads are coalesced float4 (lane-stride 16B).
// t-tile of 60 rows -> 2450 blocks (~9.6/CU). Nontemporal output stores.
#define TTILE 60
#define NT4 (NTOT / 4)        // 62500
__global__ void __launch_bounds__(256) out_kernel(const float* __restrict__ WT,
                                                  const float* __restrict__ spikes,
                                                  float* __restrict__ out) {
  __shared__ float s[TTILE * UU];
  const int t0 = blockIdx.y * TTILE;
  for (int i = threadIdx.x; i < TTILE * UU; i += 256)
    s[i] = spikes[t0 * UU + i];
  __syncthreads();

  const int n4 = blockIdx.x * 256 + threadIdx.x;
  if (n4 >= NT4) return;
  const int n = n4 * 4;

  f32x4 w[UU];
#pragma unroll
  for (int u = 0; u < UU; ++u)
    w[u] = *reinterpret_cast<const f32x4*>(&WT[(size_t)u * NTOT + n]);

  float* op = &out[(size_t)t0 * NTOT + n];
  for (int t = 0; t < TTILE; ++t) {
    f32x4 acc = (f32x4)(0.f);
#pragma unroll
    for (int u = 0; u < UU; ++u) {
      const float sv = s[t * UU + u];
      acc.x = fmaf(sv, w[u].x, acc.x);
      acc.y = fmaf(sv, w[u].y, acc.y);
      acc.z = fmaf(sv, w[u].z, acc.z);
      acc.w = fmaf(sv, w[u].w, acc.w);
    }
    __builtin_nontemporal_store(acc, reinterpret_cast<f32x4*>(op));
    op += NTOT;
  }
}

extern "C" void kernel_launch(void* const* d_in, const int* in_sizes, int n_in,
                              void* d_out, int out_size, void* d_ws, size_t ws_size,
                              hipStream_t stream) {
  // Input order: inp, w_v1, rows_v1, cols_v1, w_lm, rows_lm, cols_lm
  const float* w_v1    = (const float*)d_in[1];
  const int*   rows_v1 = (const int*)d_in[2];
  const int*   cols_v1 = (const int*)d_in[3];
  const float* w_lm    = (const float*)d_in[4];
  const int*   rows_lm = (const int*)d_in[5];
  const int*   cols_lm = (const int*)d_in[6];
  float* out = (float*)d_out;

  // Workspace: WT (10 x 250000 f32 = 10 MB) then spikes (6000 f32)
  float* WT = (float*)d_ws;
  float* spikes = WT + (size_t)NTOT * UU;
  const size_t need = ((size_t)NTOT * UU + NELEM) * sizeof(float);
  if (ws_size < need) return;

  zeroW_kernel<<<(WZ4 + 255) / 256, 256, 0, stream>>>((f32x4*)WT);
  spikes_kernel<<<(NELEM + 255) / 256, 256, 0, stream>>>(spikes);
  scatter_kernel<<<(NNZTOT + 255) / 256, 256, 0, stream>>>(w_v1, rows_v1, cols_v1,
                                                           w_lm, rows_lm, cols_lm, WT);
  dim3 grid((NT4 + 255) / 256, TLEN / TTILE);
  out_kernel<<<grid, 256, 0, stream>>>(WT, spikes, out);
}